// Round 1
// baseline (318.727 us; speedup 1.0000x reference)
//
#include <hip/hip_runtime.h>
#include <stdint.h>

#define T      3072
#define CH     64
#define HEADS  32
#define WIDTH  1536
#define BM     64
#define BN     128
#define KSTR   72     // 64 + 8 pad (bf16 elems)
#define VSTR   136    // 128 + 8 pad
#define PSTR   136    // 128 + 8 pad

typedef unsigned short u16;
typedef short short8 __attribute__((ext_vector_type(8)));   // 8 bf16 as i16 (guide-verified frag type)
typedef float floatx4 __attribute__((ext_vector_type(4)));

__device__ __forceinline__ u16 f2b(float f) {   // fp32 -> bf16 bits, RNE
  union { float f; unsigned u; } x; x.f = f;
  unsigned u = x.u;
  return (u16)((u + 0x7fffu + ((u >> 16) & 1u)) >> 16);
}

// ---------------- pre-pass: fp32 qkv -> bf16 Qt/Kt (t,ch) and V (ch,t) ----------------
// grid (48 t-tiles, 32 heads, 3 roles), 256 threads
__global__ __launch_bounds__(256) void prepass(
    const float* __restrict__ qkv, u16* __restrict__ Qt,
    u16* __restrict__ Kt, u16* __restrict__ Vo) {
  __shared__ float tile[64][65];
  const int ttile = blockIdx.x, hh = blockIdx.y, role = blockIdx.z;
  const int b = hh >> 3, h = hh & 7;
  const int t0 = ttile * 64;
  const int tid = threadIdx.x;
  const float* src = qkv + (size_t)(b * WIDTH + role * 512 + h * CH) * T;

  if (role == 2) {                       // V: straight cast-copy, keep (ch, t)
    const int c = tid >> 2, seg = (tid & 3) * 16;
    const float4* s4 = (const float4*)(src + (size_t)c * T + t0 + seg);
    u16 o[16];
#pragma unroll
    for (int i = 0; i < 4; ++i) {
      float4 v = s4[i];
      o[4*i+0] = f2b(v.x); o[4*i+1] = f2b(v.y);
      o[4*i+2] = f2b(v.z); o[4*i+3] = f2b(v.w);
    }
    uint4* d = (uint4*)(Vo + (size_t)hh * CH * T + (size_t)c * T + t0 + seg);
    d[0] = *(uint4*)&o[0];
    d[1] = *(uint4*)&o[8];
  } else {                               // Q/K: LDS-tiled transpose to (t, ch)
    const int c = tid >> 2, seg = (tid & 3) * 16;
    const float4* s4 = (const float4*)(src + (size_t)c * T + t0 + seg);
#pragma unroll
    for (int i = 0; i < 4; ++i) {
      float4 v = s4[i];
      tile[c][seg + 4*i + 0] = v.x; tile[c][seg + 4*i + 1] = v.y;
      tile[c][seg + 4*i + 2] = v.z; tile[c][seg + 4*i + 3] = v.w;
    }
    __syncthreads();
    // Q gets full logit scale (1/8) * log2(e) folded in; K is unscaled
    const float scale = (role == 0) ? 0.18033688011112042f : 1.0f;
    const int t = tid >> 2, cs = (tid & 3) * 16;
    u16 o[16];
#pragma unroll
    for (int i = 0; i < 16; ++i) o[i] = f2b(tile[cs + i][t] * scale);
    u16* dst = (role == 0 ? Qt : Kt) + (size_t)hh * T * CH + (size_t)(t0 + t) * CH + cs;
    ((uint4*)dst)[0] = *(uint4*)&o[0];
    ((uint4*)dst)[1] = *(uint4*)&o[8];
  }
}

// ---------------- flash attention: BM=64 q-rows/block, 4 waves, BN=128 ----------------
// grid (48 q-tiles, 32 heads), 256 threads
__global__ __launch_bounds__(256, 3) void attn(
    const u16* __restrict__ Qt, const u16* __restrict__ Kt,
    const u16* __restrict__ Vg, float* __restrict__ out) {
  __shared__ __align__(16) u16 KtL[BN * KSTR];        // [s][c] padded
  __shared__ __align__(16) u16 VL[CH * VSTR];         // [c][s] padded
  __shared__ __align__(16) u16 PL[4][16 * PSTR];      // per-wave [t][s]

  const int qtile = blockIdx.x, hh = blockIdx.y;
  const int tid = threadIdx.x;
  const int wave = tid >> 6, lane = tid & 63;
  const int l15 = lane & 15, quad = lane >> 4;
  const int t0 = qtile * BM;

  const u16* Qh = Qt + (size_t)hh * T * CH;
  const u16* Kh = Kt + (size_t)hh * T * CH;
  const u16* Vh = Vg + (size_t)hh * CH * T;

  // Q A-frags resident in regs for the whole block: A[m=l15][k=quad*8+j]
  const short8 qf0 = *(const short8*)(Qh + (size_t)(t0 + wave * 16 + l15) * CH + quad * 8);
  const short8 qf1 = *(const short8*)(Qh + (size_t)(t0 + wave * 16 + l15) * CH + 32 + quad * 8);

  floatx4 oacc[4] = {{0,0,0,0},{0,0,0,0},{0,0,0,0},{0,0,0,0}};
  float mrow[4] = {-1e30f,-1e30f,-1e30f,-1e30f};
  float lrow[4] = {0.f,0.f,0.f,0.f};

  const int ks_s = tid >> 1, ks_c = (tid & 1) * 32;   // K staging: half-row per thread
  const int vs_c = tid >> 2, vs_o = (tid & 3) * 32;   // V staging: quarter-row per thread

  for (int s0 = 0; s0 < T; s0 += BN) {
    __syncthreads();
    {
      const uint4* g  = (const uint4*)(Kh + (size_t)(s0 + ks_s) * CH + ks_c);
      uint4 a0 = g[0], a1 = g[1], a2 = g[2], a3 = g[3];
      const uint4* gv = (const uint4*)(Vh + (size_t)vs_c * T + s0 + vs_o);
      uint4 b0 = gv[0], b1 = gv[1], b2 = gv[2], b3 = gv[3];
      uint4* d  = (uint4*)(KtL + ks_s * KSTR + ks_c);
      d[0] = a0; d[1] = a1; d[2] = a2; d[3] = a3;
      uint4* dv = (uint4*)(VL + vs_c * VSTR + vs_o);
      dv[0] = b0; dv[1] = b1; dv[2] = b2; dv[3] = b3;
    }
    __syncthreads();

    // S = Q^T K : 8 n-tiles x (K=64 -> 2 chained MFMAs)
    floatx4 sacc[8];
#pragma unroll
    for (int nt = 0; nt < 8; ++nt) {
      const short8 kf0 = *(const short8*)(KtL + (nt * 16 + l15) * KSTR + quad * 8);
      const short8 kf1 = *(const short8*)(KtL + (nt * 16 + l15) * KSTR + 32 + quad * 8);
      floatx4 z = {0.f, 0.f, 0.f, 0.f};
      z = __builtin_amdgcn_mfma_f32_16x16x32_bf16(qf0, kf0, z, 0, 0, 0);
      z = __builtin_amdgcn_mfma_f32_16x16x32_bf16(qf1, kf1, z, 0, 0, 0);
      sacc[nt] = z;
    }

    // online softmax (base-2; log2e folded into Q). Row t = quad*4+r, col s = nt*16+l15.
    float alpha[4];
#pragma unroll
    for (int r = 0; r < 4; ++r) {
      float m = sacc[0][r];
#pragma unroll
      for (int nt = 1; nt < 8; ++nt) m = fmaxf(m, sacc[nt][r]);
#pragma unroll
      for (int i = 0; i < 4; ++i) m = fmaxf(m, __shfl_xor(m, 1 << i, 64));
      float mn = fmaxf(mrow[r], m);
      alpha[r] = __builtin_amdgcn_exp2f(mrow[r] - mn);
      mrow[r] = mn;
    }

    u16* plw = PL[wave];
#pragma unroll
    for (int r = 0; r < 4; ++r) {
      float s = 0.f;
#pragma unroll
      for (int nt = 0; nt < 8; ++nt) {
        float p = __builtin_amdgcn_exp2f(sacc[nt][r] - mrow[r]);
        s += p;
        plw[(quad * 4 + r) * PSTR + nt * 16 + l15] = f2b(p);
      }
#pragma unroll
      for (int i = 0; i < 4; ++i) s += __shfl_xor(s, 1 << i, 64);
      lrow[r] = lrow[r] * alpha[r] + s;
    }

    // rescale O: need alpha of row t = l15 (O columns are t)
    float a0 = __shfl(alpha[0], (l15 >> 2) * 16, 64);
    float a1 = __shfl(alpha[1], (l15 >> 2) * 16, 64);
    float a2 = __shfl(alpha[2], (l15 >> 2) * 16, 64);
    float a3 = __shfl(alpha[3], (l15 >> 2) * 16, 64);
    const int rs = l15 & 3;
    float av = rs == 0 ? a0 : (rs == 1 ? a1 : (rs == 2 ? a2 : a3));
#pragma unroll
    for (int mt = 0; mt < 4; ++mt) oacc[mt] = oacc[mt] * av;

    // O^T[c][t] += V * P^T : A = V (ch,s layout), B = P ((t,s) layout)
#pragma unroll
    for (int ks = 0; ks < 4; ++ks) {
      const short8 pf = *(const short8*)(plw + l15 * PSTR + ks * 32 + quad * 8);
#pragma unroll
      for (int mt = 0; mt < 4; ++mt) {
        const short8 vf = *(const short8*)(VL + (mt * 16 + l15) * VSTR + ks * 32 + quad * 8);
        oacc[mt] = __builtin_amdgcn_mfma_f32_16x16x32_bf16(vf, pf, oacc[mt], 0, 0, 0);
      }
    }
  }

  // epilogue: divide by l(t) for this lane's column t = l15
  float l0 = __shfl(lrow[0], (l15 >> 2) * 16, 64);
  float l1 = __shfl(lrow[1], (l15 >> 2) * 16, 64);
  float l2 = __shfl(lrow[2], (l15 >> 2) * 16, 64);
  float l3 = __shfl(lrow[3], (l15 >> 2) * 16, 64);
  const int rs = l15 & 3;
  float lv = rs == 0 ? l0 : (rs == 1 ? l1 : (rs == 2 ? l2 : l3));
  const float linv = 1.0f / lv;

  const int t_global = t0 + wave * 16 + l15;
  const int band = t_global >> 10, tt = t_global & 1023;
  const int b = hh >> 3, h = hh & 7;
  float* obase = out + (size_t)band * (4 * 512 * 1024)
                     + (size_t)b * (512 * 1024)
                     + (size_t)(h * CH) * 1024 + tt;
#pragma unroll
  for (int mt = 0; mt < 4; ++mt)
#pragma unroll
    for (int r = 0; r < 4; ++r) {
      int c = mt * 16 + quad * 4 + r;
      obase[(size_t)c * 1024] = oacc[mt][r] * linv;
    }
}

extern "C" void kernel_launch(void* const* d_in, const int* in_sizes, int n_in,
                              void* d_out, int out_size, void* d_ws, size_t ws_size,
                              hipStream_t stream) {
  (void)in_sizes; (void)n_in; (void)out_size; (void)ws_size;
  const float* qkv = (const float*)d_in[0];
  u16* Qt = (u16*)d_ws;                                   // 32*3072*64 bf16
  u16* Kt = Qt + (size_t)HEADS * T * CH;
  u16* Vo = Kt + (size_t)HEADS * T * CH;
  float* out = (float*)d_out;

  prepass<<<dim3(T / 64, HEADS, 3), 256, 0, stream>>>(qkv, Qt, Kt, Vo);
  attn<<<dim3(T / BM, HEADS), 256, 0, stream>>>(Qt, Kt, Vo, out);
}